// Round 7
// baseline (545.166 us; speedup 1.0000x reference)
//
#include <hip/hip_runtime.h>

#define BATCH 32
#define LANCH 8400
#define NCLS  80
#define NGT   64
#define TOPK  13
#define NCHUNK 33          // ceil(8400/256)
#define CAP   2048         // max met>0 entries per row (rect bound: <=1979)

// ---- shared per-block GT data ----
struct GtLds {
  float4 box[NGT];
  float  ga[NGT], gcx[NGT], gcy[NGT], atg[NGT], padf[NGT];
  int    lab[NGT];
};

__device__ __forceinline__ void load_gt(GtLds& s, int b,
    const float* gt_bboxes, const int* gt_labels, const float* pad_mask, int t)
{
  if (t < NGT) {
    float4 g = reinterpret_cast<const float4*>(gt_bboxes)[b * NGT + t];
    s.box[t] = g;
    float gw = g.z - g.x, gh = g.w - g.y;
    s.ga[t]  = gw * gh;
    s.gcx[t] = (g.x + g.z) * 0.5f;
    s.gcy[t] = (g.y + g.w) * 0.5f;
    s.atg[t] = atanf(gw / gh);
    s.padf[t] = pad_mask[b * NGT + t];
    s.lab[t]  = gt_labels[b * NGT + t];
  }
}

// clipped CIoU — identical expression in all kernels so recompute is bitwise equal
__device__ __forceinline__ float ciou_core(
    float4 pb, float pa, float pcx, float pcy, float atp,
    float4 gb, float ga, float gcx, float gcy, float atg)
{
  float iw = fmaxf(fminf(gb.z, pb.z) - fmaxf(gb.x, pb.x), 0.f);
  float ih = fmaxf(fminf(gb.w, pb.w) - fmaxf(gb.y, pb.y), 0.f);
  float inter = iw * ih;
  float uni   = ga + pa - inter;
  float iou   = inter / uni;
  float wi = fmaxf(fmaxf(gb.z, pb.z) - fminf(gb.x, pb.x), 0.f);
  float hi = fmaxf(fmaxf(gb.w, pb.w) - fminf(gb.y, pb.y), 0.f);
  float diag2 = wi * wi + hi * hi + 1e-7f;
  float dx = gcx - pcx, dy = gcy - pcy;
  float diou = iou - (dx * dx + dy * dy) / diag2;
  float dat = atg - atp;
  float v = 0.40528473456935109f * dat * dat;     // 4/pi^2
  float alpha = v / (1.f - iou + v + 1e-7f);
  return fmaxf(diou - alpha * v, 0.f);            // nan_to_num + clip>=0
}

__device__ __forceinline__ float masked_ciou(
    float4 pb, float pa, float pcx, float pcy, float atp, float2 cc,
    float4 gb, float ga, float gcx, float gcy, float atg, float padf)
{
  float ltrb = fminf(fminf(cc.x - gb.x, cc.y - gb.y),
                     fminf(gb.z - cc.x, gb.w - cc.y));
  if (!(ltrb > 1e-9f) || padf == 0.f) return 0.f;
  return ciou_core(pb, pa, pcx, pcy, atp, gb, ga, gcx, gcy, atg);
}

__device__ __forceinline__ unsigned long long umax64(unsigned long long a,
                                                     unsigned long long b)
{ return a > b ? a : b; }

// ------- K1: one WAVE per (b,gt) row — rect-sparse metrics + exact top-13 -------
// Output: 13 winner entries per row: l | 0x40000000 if is_in_gts (mask-eligible)
__global__ __launch_bounds__(64) void k_rowtopk(
    const float* __restrict__ pred_scores,
    const float* __restrict__ pred_bboxes,
    const float* __restrict__ centers,
    const int*   __restrict__ gt_labels,
    const float* __restrict__ gt_bboxes,
    const float* __restrict__ pad_mask,
    int*         __restrict__ ws_top)        // (B*NGT, 16)
{
  const int bg = blockIdx.x;
  if (pad_mask[bg] == 0.f) return;           // K2 skips padded rows
  const int b = bg >> 6, lane = threadIdx.x;

  __shared__ unsigned long long s_keys[CAP];
  __shared__ int s_winl[TOPK];

  const float4 gt = reinterpret_cast<const float4*>(gt_bboxes)[bg];
  const int   lab = gt_labels[bg];
  const float gw = gt.z - gt.x, gh = gt.w - gt.y;
  const float ga = gw * gh;
  const float gcx = (gt.x + gt.z) * 0.5f, gcy = (gt.y + gt.w) * 0.5f;
  const float atg = atanf(gw / gh);

  // conservative integer rects per scale (exact float ltrb test per candidate)
  const int gdim[3] = {80, 40, 20};
  const int base[3] = {0, 6400, 8000};
  const float inv[3] = {0.125f, 0.0625f, 0.03125f};
  int i0[3], j0[3], w_[3], cum[4]; cum[0] = 0;
  for (int k = 0; k < 3; ++k) {
    int a0 = (int)floorf(gt.x * inv[k] - 0.5f) - 1; a0 = a0 < 0 ? 0 : a0;
    int a1 = (int)ceilf (gt.z * inv[k] - 0.5f) + 1; a1 = a1 > gdim[k] - 1 ? gdim[k] - 1 : a1;
    int b0 = (int)floorf(gt.y * inv[k] - 0.5f) - 1; b0 = b0 < 0 ? 0 : b0;
    int b1 = (int)ceilf (gt.w * inv[k] - 0.5f) + 1; b1 = b1 > gdim[k] - 1 ? gdim[k] - 1 : b1;
    i0[k] = a0; j0[k] = b0;
    int ww = a1 >= a0 ? a1 - a0 + 1 : 0;
    int hh = b1 >= b0 ? b1 - b0 + 1 : 0;
    w_[k] = ww;
    cum[k + 1] = cum[k] + ww * hh;
  }
  const int total = cum[3];
  const float2* cc2 = reinterpret_cast<const float2*>(centers);
  const float4* pb4 = reinterpret_cast<const float4*>(pred_bboxes) + (size_t)b * LANCH;
  const float*  sc  = pred_scores + (size_t)b * LANCH * NCLS + lab;

  // ballot-compacted candidate generation: no atomics, no barriers
  int cnt = 0;
  const unsigned long long lmask = (1ull << lane) - 1ull;
  const int iters = (total + 63) >> 6;
  for (int it = 0; it < iters; ++it) {
    const int c = it * 64 + lane;
    bool valid = false;
    unsigned long long key = 0;
    if (c < total) {
      int k = (c >= cum[1]) + (c >= cum[2]);
      int r = c - cum[k];
      int di = r % w_[k], dj = r / w_[k];
      int l = base[k] + (j0[k] + dj) * gdim[k] + (i0[k] + di);
      float2 cc = cc2[l];
      float ltrb = fminf(fminf(cc.x - gt.x, cc.y - gt.y),
                         fminf(gt.z - cc.x, gt.w - cc.y));
      if (ltrb > 1e-9f) {                        // exact reference is_in_gts
        float4 pb = pb4[l];
        float pw = pb.z - pb.x, ph = pb.w - pb.y, pa = pw * ph;
        float pcx = (pb.x + pb.z) * 0.5f, pcy = (pb.y + pb.w) * 0.5f;
        float atp = atanf(pw / ph);
        float io = ciou_core(pb, pa, pcx, pcy, atp, gt, ga, gcx, gcy, atg);
        float t2 = io * io;
        float met = sc[(size_t)l * NCLS] * (t2 * t2 * t2);   // score * iou^6
        if (met > 0.f) {
          valid = true;
          key = ((unsigned long long)__float_as_uint(met) << 32)
              | (unsigned int)(0x7FFFFFFF - l);  // desc met, asc idx
        }
      }
    }
    unsigned long long bal = __ballot(valid);
    if (valid) s_keys[cnt + __popcll(bal & lmask)] = key;
    cnt += __popcll(bal);
  }
  const int nnz  = cnt;                          // wave-uniform
  const int npos = nnz < TOPK ? nnz : TOPK;

  // per-lane register max over strided LDS slots
  unsigned long long mybest = 0;
  for (int i = lane; i < nnz; i += 64) mybest = umax64(mybest, s_keys[i]);

  for (int it = 0; it < npos; ++it) {
    unsigned long long k = mybest;
    #pragma unroll
    for (int off = 32; off > 0; off >>= 1) {
      unsigned long long o = __shfl_xor(k, off);
      if (o > k) k = o;
    }                                            // all lanes hold the max
    if (lane == 0) s_winl[it] = 0x7FFFFFFF - (int)(unsigned int)(k & 0xFFFFFFFFu);
    if (mybest == k) {                           // unique owner (key embeds l)
      mybest = 0;
      for (int i = lane; i < nnz; i += 64) {
        unsigned long long v = s_keys[i];
        if (v == k) { s_keys[i] = 0; v = 0; }
        mybest = umax64(mybest, v);
      }
    }
  }
  if (lane == 0 && npos < TOPK) {
    // all positives are winners; fill with smallest l not yet a winner
    int found = npos;
    for (int l = 0; found < TOPK && l < LANCH; ++l) {
      bool taken = false;
      for (int k = 0; k < npos; ++k) if (s_winl[k] == l) taken = true;
      if (!taken) s_winl[found++] = l;
    }
  }
  __syncthreads();                               // single wave: waitcnt only
  if (lane < TOPK) {
    int l = s_winl[lane];
    float2 cc = cc2[l];
    float ltrb = fminf(fminf(cc.x - gt.x, cc.y - gt.y),
                       fminf(gt.z - cc.x, gt.w - cc.y));
    ws_top[bg * 16 + lane] = l | ((ltrb > 1e-9f) ? 0x40000000 : 0);
  }
}

// ------- K2: one block per batch — mask build, resolution, mm/mi, packed result -------
// pack: norm_f32 << 32 | lab << 16 | first << 8 | fg
__global__ __launch_bounds__(256) void k_resolve(
    const float* __restrict__ pred_scores,
    const float* __restrict__ pred_bboxes,
    const float* __restrict__ centers,
    const int*   __restrict__ gt_labels,
    const float* __restrict__ gt_bboxes,
    const float* __restrict__ pad_mask,
    const int*   __restrict__ ws_top,
    unsigned long long* __restrict__ ws_pack)
{
  __shared__ unsigned long long s_mask[LANCH];   // 67.2 KB
  __shared__ GtLds s;
  __shared__ int s_mm[NGT], s_mi[NGT];           // float-as-int (all values >= 0)
  const int b = blockIdx.x, t = threadIdx.x;
  load_gt(s, b, gt_bboxes, gt_labels, pad_mask, t);
  if (t < NGT) { s_mm[t] = 0; s_mi[t] = 0; }
  for (int i = t; i < LANCH; i += 256) s_mask[i] = 0ull;
  __syncthreads();

  // scatter winner bits into LDS mask table
  for (int p = t; p < NGT * TOPK; p += 256) {
    int g = p / TOPK, k = p - g * TOPK;
    if (s.padf[g] == 0.f) continue;              // padded rows never wrote ws_top
    int e = ws_top[(b * NGT + g) * 16 + k];
    if (e & 0x40000000) atomicOr(&s_mask[e & 0x3FFF], 1ull << g);
  }
  __syncthreads();

  const float2* cc2 = reinterpret_cast<const float2*>(centers);
  const float4* pb4 = reinterpret_cast<const float4*>(pred_bboxes) + (size_t)b * LANCH;

  // pass 1: conflict resolution + per-gt maxima (LDS atomics)
  for (int l = t; l < LANCH; l += 256) {
    unsigned long long mb = s_mask[l];
    if (!mb) continue;
    const float4 pb = pb4[l];
    const float2 cc = cc2[l];
    const float pw = pb.z - pb.x, ph = pb.w - pb.y;
    const float pa = pw * ph;
    const float pcx = (pb.x + pb.z) * 0.5f, pcy = (pb.y + pb.w) * 0.5f;
    const float atp = atanf(pw / ph);
    const float* srow = pred_scores + ((size_t)b * LANCH + l) * NCLS;

    unsigned long long fb = mb;
    if (__popcll(mb) > 1) {
      float mx = 0.f;
      unsigned long long eq = 0;
      for (int g = 0; g < NGT; ++g) {
        if (s.padf[g] == 0.f) break;             // pad is a prefix
        float io = masked_ciou(pb, pa, pcx, pcy, atp, cc, s.box[g],
                               s.ga[g], s.gcx[g], s.gcy[g], s.atg[g], s.padf[g]);
        if (io > mx)       { mx = io; eq = 1ull << g; }
        else if (io == mx) { eq |= 1ull << g; }
      }
      fb = eq;
      s_mask[l] = eq;
    }
    unsigned long long bits = fb;
    while (bits) {
      int g = __ffsll((unsigned long long)bits) - 1;
      bits &= bits - 1;
      float io = masked_ciou(pb, pa, pcx, pcy, atp, cc, s.box[g],
                             s.ga[g], s.gcx[g], s.gcy[g], s.atg[g], s.padf[g]);
      float t2 = io * io;
      float met = srow[s.lab[g]] * (t2 * t2 * t2);
      atomicMax(&s_mm[g], __float_as_int(met));
      atomicMax(&s_mi[g], __float_as_int(io));
    }
  }
  __syncthreads();

  // pass 2: norms + dense packed write (covers zeros -> no memset anywhere)
  for (int l = t; l < LANCH; l += 256) {
    unsigned long long mb = s_mask[l];
    unsigned long long pk = (unsigned long long)NCLS << 16;   // bg: norm 0, first 0, fg 0
    if (mb) {
      const float4 pb = pb4[l];
      const float2 cc = cc2[l];
      const float pw = pb.z - pb.x, ph = pb.w - pb.y;
      const float pa = pw * ph;
      const float pcx = (pb.x + pb.z) * 0.5f, pcy = (pb.y + pb.w) * 0.5f;
      const float atp = atanf(pw / ph);
      const float* srow = pred_scores + ((size_t)b * LANCH + l) * NCLS;
      const int first = __ffsll((unsigned long long)mb) - 1;
      float norm = 0.f;
      unsigned long long bits = mb;
      while (bits) {
        int g = __ffsll((unsigned long long)bits) - 1;
        bits &= bits - 1;
        float io = masked_ciou(pb, pa, pcx, pcy, atp, cc, s.box[g],
                               s.ga[g], s.gcx[g], s.gcy[g], s.atg[g], s.padf[g]);
        float t2 = io * io;
        float met = srow[s.lab[g]] * (t2 * t2 * t2);
        norm = fmaxf(norm,
                     met / (__int_as_float(s_mm[g]) + 1e-9f) * __int_as_float(s_mi[g]));
      }
      pk = ((unsigned long long)__float_as_uint(norm) << 32)
         | ((unsigned long long)s.lab[first] << 16)
         | ((unsigned long long)first << 8) | 1ull;
    }
    ws_pack[(size_t)b * LANCH + l] = pk;
  }
}

// ---------- K3: pure stream writer — all outputs from 8 B/anchor ----------
__global__ __launch_bounds__(256) void k_write(
    const float* __restrict__ gt_bboxes,
    const unsigned long long* __restrict__ ws_pack,
    float*       __restrict__ out_labels,
    float*       __restrict__ out_bboxes,
    float*       __restrict__ out_fg,
    float*       __restrict__ out_scores)
{
  __shared__ float4 s_box[NGT];
  __shared__ float  s_norm[256];
  __shared__ int    s_lab[256];
  const int b = blockIdx.y, t = threadIdx.x;
  if (t < NGT) s_box[t] = reinterpret_cast<const float4*>(gt_bboxes)[b * NGT + t];
  __syncthreads();
  const int l0 = blockIdx.x * 256;
  const int l  = l0 + t;
  const bool act = (l < LANCH);

  float norm = 0.f;
  int   lab  = NCLS;
  if (act) {
    const int idx = b * LANCH + l;
    const unsigned long long pk = ws_pack[idx];
    norm = __uint_as_float((unsigned int)(pk >> 32));
    lab  = (int)((pk >> 16) & 0xFFFF);
    const int first = (int)((pk >> 8) & 0xFF);
    out_labels[idx] = (float)lab;
    reinterpret_cast<float4*>(out_bboxes)[idx] = s_box[first];
    out_fg[idx] = (float)(pk & 1ull);
  }
  s_norm[t] = norm;
  s_lab[t]  = lab;                               // NCLS for bg -> no slot match
  __syncthreads();

  // cooperative coalesced write of the 256x80 score tile (float4 granularity)
  const int QC = NCLS / 4;                       // 20 float4 columns
  float4* tile = reinterpret_cast<float4*>(out_scores + ((size_t)b * LANCH + l0) * NCLS);
  const int amax = (LANCH - l0) < 256 ? (LANCH - l0) : 256;
  #pragma unroll
  for (int k = 0; k < QC; ++k) {
    int p = k * 256 + t;                         // tile float4 index
    int a = p / QC, c4 = p - a * QC;             // anchor row, float4 col
    if (a < amax) {
      float4 wv = make_float4(0.f, 0.f, 0.f, 0.f);
      int la = s_lab[a], base = c4 * 4;
      if (la >= base && la < base + 4) (&wv.x)[la - base] = s_norm[a];
      tile[p] = wv;
    }
  }
}

extern "C" void kernel_launch(void* const* d_in, const int* in_sizes, int n_in,
                              void* d_out, int out_size, void* d_ws, size_t ws_size,
                              hipStream_t stream) {
  const float* pred_scores = (const float*)d_in[0];
  const float* pred_bboxes = (const float*)d_in[1];
  const float* centers     = (const float*)d_in[2];
  const int*   gt_labels   = (const int*)  d_in[3];
  const float* gt_bboxes   = (const float*)d_in[4];
  const float* pad_mask    = (const float*)d_in[5];

  char* ws = (char*)d_ws;
  int* ws_top = (int*)ws;                                           // 2048*16*4 = 128 KB
  unsigned long long* ws_pack =
      (unsigned long long*)(ws + (size_t)BATCH * NGT * 16 * 4);     // 2.15 MB

  float* out        = (float*)d_out;
  float* out_labels = out;
  float* out_bboxes = out + (size_t)BATCH * LANCH;
  float* out_scores = out + (size_t)BATCH * LANCH * 5;
  float* out_fg     = out + (size_t)BATCH * LANCH * 5 + (size_t)BATCH * LANCH * NCLS;

  k_rowtopk<<<BATCH * NGT, 64, 0, stream>>>(pred_scores, pred_bboxes, centers,
      gt_labels, gt_bboxes, pad_mask, ws_top);

  k_resolve<<<BATCH, 256, 0, stream>>>(pred_scores, pred_bboxes, centers,
      gt_labels, gt_bboxes, pad_mask, ws_top, ws_pack);

  dim3 grid(NCHUNK, BATCH);
  k_write<<<grid, 256, 0, stream>>>(gt_bboxes, ws_pack,
      out_labels, out_bboxes, out_fg, out_scores);
}

// Round 8
// 229.923 us; speedup vs baseline: 2.3711x; 2.3711x over previous
//
#include <hip/hip_runtime.h>

#define BATCH 32
#define LANCH 8400
#define NCLS  80
#define NGT   64
#define TOPK  13
#define NCHUNK 33          // ceil(8400/256)
#define CAP   2048         // max met>0 entries per row (rect bound: <=1979)

// ---- shared per-block GT data ----
struct GtLds {
  float4 box[NGT];
  float  ga[NGT], gcx[NGT], gcy[NGT], atg[NGT], padf[NGT];
  int    lab[NGT];
};

__device__ __forceinline__ void load_gt(GtLds& s, int b,
    const float* gt_bboxes, const int* gt_labels, const float* pad_mask, int t)
{
  if (t < NGT) {
    float4 g = reinterpret_cast<const float4*>(gt_bboxes)[b * NGT + t];
    s.box[t] = g;
    float gw = g.z - g.x, gh = g.w - g.y;
    s.ga[t]  = gw * gh;
    s.gcx[t] = (g.x + g.z) * 0.5f;
    s.gcy[t] = (g.y + g.w) * 0.5f;
    s.atg[t] = atanf(gw / gh);
    s.padf[t] = pad_mask[b * NGT + t];
    s.lab[t]  = gt_labels[b * NGT + t];
  }
}

// clipped CIoU — identical expression in all kernels so recompute is bitwise equal
__device__ __forceinline__ float ciou_core(
    float4 pb, float pa, float pcx, float pcy, float atp,
    float4 gb, float ga, float gcx, float gcy, float atg)
{
  float iw = fmaxf(fminf(gb.z, pb.z) - fmaxf(gb.x, pb.x), 0.f);
  float ih = fmaxf(fminf(gb.w, pb.w) - fmaxf(gb.y, pb.y), 0.f);
  float inter = iw * ih;
  float uni   = ga + pa - inter;
  float iou   = inter / uni;
  float wi = fmaxf(fmaxf(gb.z, pb.z) - fminf(gb.x, pb.x), 0.f);
  float hi = fmaxf(fmaxf(gb.w, pb.w) - fminf(gb.y, pb.y), 0.f);
  float diag2 = wi * wi + hi * hi + 1e-7f;
  float dx = gcx - pcx, dy = gcy - pcy;
  float diou = iou - (dx * dx + dy * dy) / diag2;
  float dat = atg - atp;
  float v = 0.40528473456935109f * dat * dat;     // 4/pi^2
  float alpha = v / (1.f - iou + v + 1e-7f);
  return fmaxf(diou - alpha * v, 0.f);            // nan_to_num + clip>=0
}

__device__ __forceinline__ float masked_ciou(
    float4 pb, float pa, float pcx, float pcy, float atp, float2 cc,
    float4 gb, float ga, float gcx, float gcy, float atg, float padf)
{
  float ltrb = fminf(fminf(cc.x - gb.x, cc.y - gb.y),
                     fminf(gb.z - cc.x, gb.w - cc.y));
  if (!(ltrb > 1e-9f) || padf == 0.f) return 0.f;
  return ciou_core(pb, pa, pcx, pcy, atp, gb, ga, gcx, gcy, atg);
}

__device__ __forceinline__ unsigned long long umax64(unsigned long long a,
                                                     unsigned long long b)
{ return a > b ? a : b; }

// ------- K1: one WAVE per (b,gt) row — rect-sparse metrics + exact top-13 -------
__global__ __launch_bounds__(64) void k_rowtopk(
    const float* __restrict__ pred_scores,
    const float* __restrict__ pred_bboxes,
    const float* __restrict__ centers,
    const int*   __restrict__ gt_labels,
    const float* __restrict__ gt_bboxes,
    const float* __restrict__ pad_mask,
    unsigned long long* __restrict__ mask64)
{
  const int bg = blockIdx.x;
  if (pad_mask[bg] == 0.f) return;
  const int b = bg >> 6, g = bg & 63, lane = threadIdx.x;

  __shared__ unsigned long long s_keys[CAP];
  __shared__ int s_winl[TOPK];

  const float4 gt = reinterpret_cast<const float4*>(gt_bboxes)[bg];
  const int   lab = gt_labels[bg];
  const float gw = gt.z - gt.x, gh = gt.w - gt.y;
  const float ga = gw * gh;
  const float gcx = (gt.x + gt.z) * 0.5f, gcy = (gt.y + gt.w) * 0.5f;
  const float atg = atanf(gw / gh);

  // conservative integer rects per scale (exact float ltrb test per candidate)
  const int gdim[3] = {80, 40, 20};
  const int base[3] = {0, 6400, 8000};
  const float inv[3] = {0.125f, 0.0625f, 0.03125f};
  int i0[3], j0[3], w_[3], cum[4]; cum[0] = 0;
  for (int k = 0; k < 3; ++k) {
    int a0 = (int)floorf(gt.x * inv[k] - 0.5f) - 1; a0 = a0 < 0 ? 0 : a0;
    int a1 = (int)ceilf (gt.z * inv[k] - 0.5f) + 1; a1 = a1 > gdim[k] - 1 ? gdim[k] - 1 : a1;
    int b0 = (int)floorf(gt.y * inv[k] - 0.5f) - 1; b0 = b0 < 0 ? 0 : b0;
    int b1 = (int)ceilf (gt.w * inv[k] - 0.5f) + 1; b1 = b1 > gdim[k] - 1 ? gdim[k] - 1 : b1;
    i0[k] = a0; j0[k] = b0;
    int ww = a1 >= a0 ? a1 - a0 + 1 : 0;
    int hh = b1 >= b0 ? b1 - b0 + 1 : 0;
    w_[k] = ww;
    cum[k + 1] = cum[k] + ww * hh;
  }
  const int total = cum[3];
  const float2* cc2 = reinterpret_cast<const float2*>(centers);
  const float4* pb4 = reinterpret_cast<const float4*>(pred_bboxes) + (size_t)b * LANCH;
  const float*  sc  = pred_scores + (size_t)b * LANCH * NCLS + lab;

  // ballot-compacted candidate generation: no atomics, no barriers
  int cnt = 0;
  const unsigned long long lmask = (1ull << lane) - 1ull;
  const int iters = (total + 63) >> 6;
  for (int it = 0; it < iters; ++it) {
    const int c = it * 64 + lane;
    bool valid = false;
    unsigned long long key = 0;
    if (c < total) {
      int k = (c >= cum[1]) + (c >= cum[2]);
      int r = c - cum[k];
      int di = r % w_[k], dj = r / w_[k];
      int l = base[k] + (j0[k] + dj) * gdim[k] + (i0[k] + di);
      float2 cc = cc2[l];
      float ltrb = fminf(fminf(cc.x - gt.x, cc.y - gt.y),
                         fminf(gt.z - cc.x, gt.w - cc.y));
      if (ltrb > 1e-9f) {                        // exact reference is_in_gts
        float4 pb = pb4[l];
        float pw = pb.z - pb.x, ph = pb.w - pb.y, pa = pw * ph;
        float pcx = (pb.x + pb.z) * 0.5f, pcy = (pb.y + pb.w) * 0.5f;
        float atp = atanf(pw / ph);
        float io = ciou_core(pb, pa, pcx, pcy, atp, gt, ga, gcx, gcy, atg);
        float t2 = io * io;
        float met = sc[(size_t)l * NCLS] * (t2 * t2 * t2);   // score * iou^6
        if (met > 0.f) {
          valid = true;
          key = ((unsigned long long)__float_as_uint(met) << 32)
              | (unsigned int)(0x7FFFFFFF - l);  // desc met, asc idx
        }
      }
    }
    unsigned long long bal = __ballot(valid);
    if (valid) s_keys[cnt + __popcll(bal & lmask)] = key;
    cnt += __popcll(bal);
  }
  const int nnz  = cnt;                          // wave-uniform
  const int npos = nnz < TOPK ? nnz : TOPK;

  // per-lane register max over strided LDS slots
  unsigned long long mybest = 0;
  for (int i = lane; i < nnz; i += 64) mybest = umax64(mybest, s_keys[i]);

  for (int it = 0; it < npos; ++it) {
    unsigned long long k = mybest;
    #pragma unroll
    for (int off = 32; off > 0; off >>= 1) {
      unsigned long long o = __shfl_xor(k, off);
      if (o > k) k = o;
    }                                            // all lanes hold the max
    if (lane == 0) s_winl[it] = 0x7FFFFFFF - (int)(unsigned int)(k & 0xFFFFFFFFu);
    if (mybest == k) {                           // unique owner (key embeds l)
      mybest = 0;
      for (int i = lane; i < nnz; i += 64) {
        unsigned long long v = s_keys[i];
        if (v == k) { s_keys[i] = 0; v = 0; }
        mybest = umax64(mybest, v);
      }
    }
  }
  if (lane == 0 && npos < TOPK) {
    // all positives are winners; fill with smallest l not yet a winner
    int found = npos;
    for (int l = 0; found < TOPK && l < LANCH; ++l) {
      bool taken = false;
      for (int k = 0; k < npos; ++k) if (s_winl[k] == l) taken = true;
      if (!taken) s_winl[found++] = l;
    }
  }
  __syncthreads();                               // single wave: waitcnt only
  if (lane < TOPK) {
    int l = s_winl[lane];
    float2 cc = cc2[l];
    float ltrb = fminf(fminf(cc.x - gt.x, cc.y - gt.y),
                       fminf(gt.z - cc.x, gt.w - cc.y));
    if (ltrb > 1e-9f)                            // winner's is_in_gts
      atomicOr(&mask64[(size_t)b * LANCH + l], 1ull << g);
  }
}

// ------- K2: SPARSE conflict resolution + per-gt maxima (dense grid, 97% exit) -------
__global__ __launch_bounds__(256) void k_resolve(
    const float* __restrict__ pred_scores,
    const float* __restrict__ pred_bboxes,
    const float* __restrict__ centers,
    const int*   __restrict__ gt_labels,
    const float* __restrict__ gt_bboxes,
    const float* __restrict__ pad_mask,
    unsigned long long* __restrict__ mask64,
    float*       __restrict__ ws_mm,
    float*       __restrict__ ws_mi)
{
  __shared__ GtLds s;
  const int b = blockIdx.y, t = threadIdx.x;
  load_gt(s, b, gt_bboxes, gt_labels, pad_mask, t);
  __syncthreads();
  const int l = blockIdx.x * 256 + t;
  if (l >= LANCH) return;
  const int idx = b * LANCH + l;

  unsigned long long mb = mask64[idx];
  if (mb == 0ull) return;                 // ~97% of anchors
  const int sum1 = __popcll(mb);

  const float4 pb = reinterpret_cast<const float4*>(pred_bboxes)[(size_t)b * LANCH + l];
  const float2 cc = reinterpret_cast<const float2*>(centers)[l];
  const float pw = pb.z - pb.x, ph = pb.w - pb.y;
  const float pa = pw * ph;
  const float pcx = (pb.x + pb.z) * 0.5f, pcy = (pb.y + pb.w) * 0.5f;
  const float atp = atanf(pw / ph);
  const float* srow = pred_scores + ((size_t)b * LANCH + l) * NCLS;

  unsigned long long fb = mb;
  if (sum1 > 1) {
    float mx = 0.f;
    unsigned long long eq = 0;
    for (int g = 0; g < NGT; ++g) {
      if (s.padf[g] == 0.f) break;        // pad is a prefix
      float io = masked_ciou(pb, pa, pcx, pcy, atp, cc, s.box[g],
                             s.ga[g], s.gcx[g], s.gcy[g], s.atg[g], s.padf[g]);
      if (io > mx)       { mx = io; eq = 1ull << g; }
      else if (io == mx) { eq |= 1ull << g; }
    }
    fb = eq;
    mask64[idx] = eq;
  }

  unsigned long long bits = fb;
  while (bits) {
    int g = __ffsll((unsigned long long)bits) - 1;
    bits &= bits - 1;
    float io = masked_ciou(pb, pa, pcx, pcy, atp, cc, s.box[g],
                           s.ga[g], s.gcx[g], s.gcy[g], s.atg[g], s.padf[g]);
    float t2 = io * io;
    float met = srow[s.lab[g]] * (t2 * t2 * t2);
    atomicMax(reinterpret_cast<int*>(ws_mm + b * NGT + g), __float_as_int(met));
    atomicMax(reinterpret_cast<int*>(ws_mi + b * NGT + g), __float_as_int(io));
  }
}

// ---------- K3: single DENSE writer — labels/bboxes/fg + coalesced score tile ----------
__global__ __launch_bounds__(256) void k_write(
    const float* __restrict__ pred_scores,
    const float* __restrict__ pred_bboxes,
    const float* __restrict__ centers,
    const int*   __restrict__ gt_labels,
    const float* __restrict__ gt_bboxes,
    const float* __restrict__ pad_mask,
    const unsigned long long* __restrict__ mask64,
    const float* __restrict__ ws_mm,
    const float* __restrict__ ws_mi,
    float*       __restrict__ out_labels,
    float*       __restrict__ out_bboxes,
    float*       __restrict__ out_fg,
    float*       __restrict__ out_scores)
{
  __shared__ GtLds s;
  __shared__ float smm[NGT], smi[NGT];
  __shared__ float s_norm[256];
  __shared__ int   s_lab[256];
  const int b = blockIdx.y, t = threadIdx.x;
  load_gt(s, b, gt_bboxes, gt_labels, pad_mask, t);
  if (t < NGT) { smm[t] = ws_mm[b * NGT + t]; smi[t] = ws_mi[b * NGT + t]; }
  __syncthreads();
  const int l0 = blockIdx.x * 256;
  const int l  = l0 + t;
  const bool act = (l < LANCH);

  float norm = 0.f;
  int   lab  = NCLS;
  if (act) {
    const int idx = b * LANCH + l;
    unsigned long long bits = mask64[idx];
    if (bits != 0ull) {
      const float4 pb = reinterpret_cast<const float4*>(pred_bboxes)[(size_t)b * LANCH + l];
      const float2 cc = reinterpret_cast<const float2*>(centers)[l];
      const float pw = pb.z - pb.x, ph = pb.w - pb.y;
      const float pa = pw * ph;
      const float pcx = (pb.x + pb.z) * 0.5f, pcy = (pb.y + pb.w) * 0.5f;
      const float atp = atanf(pw / ph);
      const float* srow = pred_scores + ((size_t)b * LANCH + l) * NCLS;
      const int first = __ffsll((unsigned long long)bits) - 1;
      lab = s.lab[first];
      unsigned long long bb = bits;
      while (bb) {
        int g = __ffsll((unsigned long long)bb) - 1;
        bb &= bb - 1;
        float io = masked_ciou(pb, pa, pcx, pcy, atp, cc, s.box[g],
                               s.ga[g], s.gcx[g], s.gcy[g], s.atg[g], s.padf[g]);
        float t2 = io * io;
        float met = srow[s.lab[g]] * (t2 * t2 * t2);
        norm = fmaxf(norm, met / (smm[g] + 1e-9f) * smi[g]);
      }
      out_labels[idx] = (float)lab;
      reinterpret_cast<float4*>(out_bboxes)[idx] = s.box[first];
      out_fg[idx] = 1.f;
    } else {
      out_labels[idx] = (float)NCLS;
      reinterpret_cast<float4*>(out_bboxes)[idx] = s.box[0];
      out_fg[idx] = 0.f;
    }
  }
  s_norm[t] = norm;
  s_lab[t]  = lab;          // NCLS for bg -> never matches a slot
  __syncthreads();

  // cooperative coalesced write of the 256x80 score tile (float4 granularity)
  const int QC = NCLS / 4;                       // 20 float4 columns
  float4* tile = reinterpret_cast<float4*>(out_scores + ((size_t)b * LANCH + l0) * NCLS);
  const int amax = (LANCH - l0) < 256 ? (LANCH - l0) : 256;
  #pragma unroll
  for (int k = 0; k < QC; ++k) {
    int p = k * 256 + t;                         // tile float4 index
    int a = p / QC, c4 = p - a * QC;             // anchor row, float4 col
    if (a < amax) {
      float4 wv = make_float4(0.f, 0.f, 0.f, 0.f);
      int la = s_lab[a], base = c4 * 4;
      if (la >= base && la < base + 4) (&wv.x)[la - base] = s_norm[a];
      tile[p] = wv;
    }
  }
}

extern "C" void kernel_launch(void* const* d_in, const int* in_sizes, int n_in,
                              void* d_out, int out_size, void* d_ws, size_t ws_size,
                              hipStream_t stream) {
  const float* pred_scores = (const float*)d_in[0];
  const float* pred_bboxes = (const float*)d_in[1];
  const float* centers     = (const float*)d_in[2];
  const int*   gt_labels   = (const int*)  d_in[3];
  const float* gt_bboxes   = (const float*)d_in[4];
  const float* pad_mask    = (const float*)d_in[5];

  char* ws = (char*)d_ws;
  unsigned long long* mask64 = (unsigned long long*)ws;             // 2.15 MB
  float* ws_mm = (float*)(ws + (size_t)BATCH * LANCH * 8);
  float* ws_mi = ws_mm + BATCH * NGT;
  const size_t zero_bytes = (size_t)BATCH * LANCH * 8 + 2 * BATCH * NGT * sizeof(float);

  float* out        = (float*)d_out;
  float* out_labels = out;
  float* out_bboxes = out + (size_t)BATCH * LANCH;
  float* out_scores = out + (size_t)BATCH * LANCH * 5;
  float* out_fg     = out + (size_t)BATCH * LANCH * 5 + (size_t)BATCH * LANCH * NCLS;

  hipMemsetAsync(ws, 0, zero_bytes, stream);   // mask64 + mm + mi

  k_rowtopk<<<BATCH * NGT, 64, 0, stream>>>(pred_scores, pred_bboxes, centers,
      gt_labels, gt_bboxes, pad_mask, mask64);

  dim3 grid(NCHUNK, BATCH);
  k_resolve<<<grid, 256, 0, stream>>>(pred_scores, pred_bboxes, centers,
      gt_labels, gt_bboxes, pad_mask, mask64, ws_mm, ws_mi);

  k_write<<<grid, 256, 0, stream>>>(pred_scores, pred_bboxes, centers,
      gt_labels, gt_bboxes, pad_mask, mask64, ws_mm, ws_mi,
      out_labels, out_bboxes, out_fg, out_scores);
}